// Round 5
// baseline (280.585 us; speedup 1.0000x reference)
//
#include <hip/hip_runtime.h>
#include <cstdint>

typedef unsigned short u16;
typedef __attribute__((ext_vector_type(8))) short short8;
typedef __attribute__((ext_vector_type(4))) float f32x4;

#if __has_builtin(__builtin_amdgcn_exp2f)
#define EXP2F(x) __builtin_amdgcn_exp2f(x)
#else
#define EXP2F(x) exp2f(x)
#endif

// fp32 -> bf16 bits, round-to-nearest-even
__device__ inline u16 f2bf(float f) {
  union { float f; unsigned u; } v; v.f = f;
  unsigned u = v.u;
  return (u16)((u + 0x7fffu + ((u >> 16) & 1u)) >> 16);
}

// pack two fp32 -> bf16x2 (a -> low half); round-half-up via +0x8000 then
// v_perm_b32 grabs the two high halves in one op. Only used for P (P > 0).
__device__ inline unsigned pk2bf_fast(float a, float b) {
  union { float f; unsigned u; } ua, ub; ua.f = a; ub.f = b;
  return __builtin_amdgcn_perm(ub.u + 0x8000u, ua.u + 0x8000u, 0x07060302u);
}

// async global -> LDS, 16B per lane (contiguous landing order only)
__device__ inline void gl2lds16(const void* g, void* l) {
  __builtin_amdgcn_global_load_lds(
      (const __attribute__((address_space(1))) unsigned int*)(unsigned long long)(uintptr_t)g,
      (__attribute__((address_space(3))) unsigned int*)(unsigned int)(uintptr_t)l,
      16, 0, 0);
}

// ---------------------------------------------------------------- cvt kernel
__global__ __launch_bounds__(256) void cvt_kernel(
    const float* __restrict__ x,
    const float* __restrict__ wq, const float* __restrict__ wk,
    const float* __restrict__ wv, const float* __restrict__ wo,
    u16* __restrict__ xb, u16* __restrict__ wqb, u16* __restrict__ wkb,
    u16* __restrict__ wvb, u16* __restrict__ wob) {
  const int y = blockIdx.y;
  const int Q = 1 << 20;
  const float* src;
  u16* dst;
  if (y < 4)       { src = x + y * Q; dst = xb + y * Q; }
  else if (y == 4) { src = wq; dst = wqb; }
  else if (y == 5) { src = wk; dst = wkb; }
  else if (y == 6) { src = wv; dst = wvb; }
  else             { src = wo; dst = wob; }
  const int i = (blockIdx.x * 256 + threadIdx.x) * 8;
  float4 a = *(const float4*)(src + i);
  float4 b = *(const float4*)(src + i + 4);
  short8 o;
  o[0] = (short)f2bf(a.x); o[1] = (short)f2bf(a.y);
  o[2] = (short)f2bf(a.z); o[3] = (short)f2bf(a.w);
  o[4] = (short)f2bf(b.x); o[5] = (short)f2bf(b.y);
  o[6] = (short)f2bf(b.z); o[7] = (short)f2bf(b.w);
  *(short8*)(dst + i) = o;
}

// ------------------------------------------------------------ QKV projection
// NT GEMM, M=4096 N=1024 K=1024; grid (8, 32, 3)
// z==0/1 -> Q/K in [B,NH,S,D]
// z==2   -> V^T in [B,NH,D,Sperm], keys sigma-permuted within 64-blocks:
//           sigma(s) = (s&15)*4 + ((s>>4)&3)  (matches attn P-write layout)
__global__ __launch_bounds__(256) void gemm_qkv(
    const u16* __restrict__ xb,
    const u16* __restrict__ wqb, const u16* __restrict__ wkb, const u16* __restrict__ wvb,
    const float* __restrict__ bq, const float* __restrict__ bk, const float* __restrict__ bv,
    u16* __restrict__ qo, u16* __restrict__ ko, u16* __restrict__ vto) {
  const int z = blockIdx.z;
  const u16* W = (z == 0) ? wqb : (z == 1) ? wkb : wvb;
  const float* bias = (z == 0) ? bq : (z == 1) ? bk : bv;

  __shared__ u16 smem[18432];
  u16* As = smem;
  u16* Bs = smem + 8192;
  const int tid = threadIdx.x, lane = tid & 63;
  const int wid = tid >> 6, wm = wid >> 1, wn = wid & 1;
  const int l15 = lane & 15, lg = lane >> 4;
  const int m0 = blockIdx.y * 128, n0 = blockIdx.x * 128;

  f32x4 acc[4][4] = {};

  for (int k0 = 0; k0 < 1024; k0 += 64) {
#pragma unroll
    for (int i = 0; i < 4; ++i) {
      int c = i * 256 + tid;
      gl2lds16(xb + (m0 + (c >> 3)) * 1024 + k0 + (c & 7) * 8, As + c * 8);
      gl2lds16(W  + (n0 + (c >> 3)) * 1024 + k0 + (c & 7) * 8, Bs + c * 8);
    }
    __syncthreads();
#pragma unroll
    for (int kk = 0; kk < 2; ++kk) {
      short8 af[4], bf[4];
#pragma unroll
      for (int mb = 0; mb < 4; ++mb)
        af[mb] = *(const short8*)(As + (wm * 64 + mb * 16 + l15) * 64 + kk * 32 + lg * 8);
#pragma unroll
      for (int nb = 0; nb < 4; ++nb)
        bf[nb] = *(const short8*)(Bs + (wn * 64 + nb * 16 + l15) * 64 + kk * 32 + lg * 8);
#pragma unroll
      for (int mb = 0; mb < 4; ++mb)
#pragma unroll
        for (int nb = 0; nb < 4; ++nb)
          acc[mb][nb] = __builtin_amdgcn_mfma_f32_16x16x32_bf16(af[mb], bf[nb], acc[mb][nb], 0, 0, 0);
    }
    __syncthreads();
  }

  if (z < 2) {
    u16* out = (z == 0) ? qo : ko;
#pragma unroll
    for (int mb = 0; mb < 4; ++mb)
#pragma unroll
      for (int nb = 0; nb < 4; ++nb)
#pragma unroll
        for (int r = 0; r < 4; ++r) {
          int m = m0 + wm * 64 + mb * 16 + lg * 4 + r;  // b*2048 + s
          int n = n0 + wn * 64 + nb * 16 + l15;         // h*64 + d
          float v = acc[mb][nb][r] + bias[n];
          int b = m >> 11, s = m & 2047, h = n >> 6, d = n & 63;
          out[((b * 16 + h) * 2048 + s) * 64 + d] = f2bf(v);
        }
  } else {
    // stage wave's 64(s) x 64(d) tile into LDS as [d][sigma(s_local)], then
    // write 16B lane-coalesced rows to global V^T.
    u16* wbuf = smem + wid * 4608;  // 64 x 72
#pragma unroll
    for (int mb = 0; mb < 4; ++mb)
#pragma unroll
      for (int nb = 0; nb < 4; ++nb) {
        int n = n0 + wn * 64 + nb * 16 + l15;
        float bn = bias[n];
        int dl = nb * 16 + l15;
#pragma unroll
        for (int r = 0; r < 4; ++r) {
          int sig = (lg * 4 + r) * 4 + mb;  // sigma of s_local = mb*16+lg*4+r
          wbuf[dl * 72 + sig] = f2bf(acc[mb][nb][r] + bn);
        }
      }
    int h_w = (n0 >> 6) + wn;
    int mbase = m0 + wm * 64;
    int b = mbase >> 11, sb = mbase & 2047;
#pragma unroll
    for (int i = 0; i < 8; ++i) {
      int dl = (lane >> 3) + 8 * i;
      int c = lane & 7;
      short8 vv = *(const short8*)(wbuf + dl * 72 + c * 8);
      *(short8*)(vto + ((b * 16 + h_w) * 64 + dl) * 2048 + sb + c * 8) = vv;
    }
  }
}

// ---------------------------------------------------------------- attention
// Barrier-free flash attention. Q-tile 128 x K-tile 64, grid (16,16,2), 256 thr.
// Q/K/V^T MFMA fragments are loaded DIRECTLY from global (coalesced 16B/lane;
// K/V tiles are L1/L2-hot). LDS is used only for the wave-private P C->A
// layout round-trip. No __syncthreads anywhere. Fixed-max softmax
// P = exp2(s*log2e/8 - 4); row-sum via ones-constant B operand (l replicated
// across all columns -> no shuffle in epilogue).
__global__ __launch_bounds__(256, 2) void attn_kernel(
    const u16* __restrict__ qg, const u16* __restrict__ kg,
    const u16* __restrict__ vtg, u16* __restrict__ ctxg) {
  const int h = blockIdx.x, qt = blockIdx.y, b = blockIdx.z;
  const int bh = b * 16 + h;
  const u16* Qg = qg + (bh * 2048 + qt * 128) * 64;
  const u16* Kg = kg + bh * 2048 * 64;
  const u16* Vg = vtg + bh * 64 * 2048;

  __shared__ u16 SP[128 * 72];  // P only; wave-private 32-row strips

  const int tid = threadIdx.x, lane = tid & 63, wid = tid >> 6;
  const int l15 = lane & 15, lg = lane >> 4;
  const int row0 = wid * 32;

  // Q fragments direct from global (reused all 32 kt)
  short8 qf[2][2];
#pragma unroll
  for (int mb = 0; mb < 2; ++mb)
#pragma unroll
    for (int kk = 0; kk < 2; ++kk)
      qf[mb][kk] = *(const short8*)(Qg + (row0 + mb * 16 + l15) * 64 + kk * 32 + lg * 8);

  // per-lane fragment base pointers
  const u16* kbase = Kg + l15 * 64 + lg * 8;    // + kt*4096 + nb*1024 + kk*32
  const u16* vbase = Vg + l15 * 2048 + lg * 8;  // + nd*32768 + kt*64 + kk*32

  short8 kf[2][4], kfn[2][4], vf[2][4];
#pragma unroll
  for (int kk = 0; kk < 2; ++kk)
#pragma unroll
    for (int nb = 0; nb < 4; ++nb) {
      kf[kk][nb] = *(const short8*)(kbase + nb * 1024 + kk * 32);
      vf[kk][nb] = *(const short8*)(vbase + nb * 32768 + kk * 32);
    }

  short8 ones8;
#pragma unroll
  for (int j = 0; j < 8; ++j) ones8[j] = (short)0x3F80;  // bf16 1.0

  f32x4 acc[2][5] = {};  // nd 0..3 = ctx, nd 4 = row-sum
  const float cexp = 0.18033688011112042f;  // log2(e)/8

#pragma unroll 2
  for (int kt = 0; kt < 32; ++kt) {
    const int ktn = (kt + 1 < 32) ? kt + 1 : 0;  // last prefetch discarded

    // S = Q K^T
    f32x4 sc[2][4] = {};
#pragma unroll
    for (int kk = 0; kk < 2; ++kk)
#pragma unroll
      for (int mb = 0; mb < 2; ++mb)
#pragma unroll
        for (int nb = 0; nb < 4; ++nb)
          sc[mb][nb] = __builtin_amdgcn_mfma_f32_16x16x32_bf16(qf[mb][kk], kf[kk][nb], sc[mb][nb], 0, 0, 0);

    // prefetch next K fragments (kf dead after QK issue; hidden by softmax)
#pragma unroll
    for (int kk = 0; kk < 2; ++kk)
#pragma unroll
      for (int nb = 0; nb < 4; ++nb)
        kfn[kk][nb] = *(const short8*)(kbase + ktn * 4096 + nb * 1024 + kk * 32);

    // P = exp2(s*c - 4); sigma(key = nb*16+l15) = l15*4+nb -> one b64 per row
#pragma unroll
    for (int mb = 0; mb < 2; ++mb)
#pragma unroll
      for (int r = 0; r < 4; ++r) {
        float p0 = EXP2F(fmaf(sc[mb][0][r], cexp, -4.0f));
        float p1 = EXP2F(fmaf(sc[mb][1][r], cexp, -4.0f));
        float p2 = EXP2F(fmaf(sc[mb][2][r], cexp, -4.0f));
        float p3 = EXP2F(fmaf(sc[mb][3][r], cexp, -4.0f));
        uint2 u;
        u.x = pk2bf_fast(p0, p1);
        u.y = pk2bf_fast(p2, p3);
        *(uint2*)(SP + (row0 + mb * 16 + lg * 4 + r) * 72 + l15 * 4) = u;
      }

    // ctx += P @ [V | 1]  (same-wave LDS write->read, in-order)
#pragma unroll
    for (int kk = 0; kk < 2; ++kk) {
      short8 pa[2];
#pragma unroll
      for (int mb = 0; mb < 2; ++mb)
        pa[mb] = *(const short8*)(SP + (row0 + mb * 16 + l15) * 72 + kk * 32 + lg * 8);
#pragma unroll
      for (int mb = 0; mb < 2; ++mb) {
#pragma unroll
        for (int nd = 0; nd < 4; ++nd)
          acc[mb][nd] = __builtin_amdgcn_mfma_f32_16x16x32_bf16(pa[mb], vf[kk][nd], acc[mb][nd], 0, 0, 0);
        acc[mb][4] = __builtin_amdgcn_mfma_f32_16x16x32_bf16(pa[mb], ones8, acc[mb][4], 0, 0, 0);
      }
    }

    // prefetch next V fragments (vf dead after PV; hidden until next PV)
#pragma unroll
    for (int kk = 0; kk < 2; ++kk)
#pragma unroll
      for (int nd = 0; nd < 4; ++nd)
        vf[kk][nd] = *(const short8*)(vbase + nd * 32768 + ktn * 64 + kk * 32);

    // rotate K buffers (copies elided by unroll-2 renaming)
#pragma unroll
    for (int kk = 0; kk < 2; ++kk)
#pragma unroll
      for (int nb = 0; nb < 4; ++nb) kf[kk][nb] = kfn[kk][nb];
  }

  // epilogue: l = acc[mb][4][r] (replicated across cols, no shuffle)
#pragma unroll
  for (int mb = 0; mb < 2; ++mb)
#pragma unroll
    for (int r = 0; r < 4; ++r) {
      float inv = 1.0f / acc[mb][4][r];
      int s = qt * 128 + row0 + mb * 16 + lg * 4 + r;
      u16* dst = ctxg + (b * 2048 + s) * 1024 + h * 64;
#pragma unroll
      for (int nd = 0; nd < 4; ++nd)
        dst[nd * 16 + l15] = f2bf(acc[mb][nd][r] * inv);
    }
}

// ------------------------------------------------------------ out projection
// out[m,n] = sum_k ctx[m,k]*Wo[n,k] + bo[n], fp32 out.
// 128m x 64n tiles -> grid (16, 32) = 512 blocks = 2/CU.
__global__ __launch_bounds__(256) void gemm_out(
    const u16* __restrict__ cb, const u16* __restrict__ wob,
    const float* __restrict__ bo, float* __restrict__ out) {
  __shared__ u16 As[128 * 64];
  __shared__ u16 Bs[64 * 64];
  const int tid = threadIdx.x, lane = tid & 63;
  const int wid = tid >> 6;
  const int l15 = lane & 15, lg = lane >> 4;
  const int m0 = blockIdx.y * 128, n0 = blockIdx.x * 64;

  f32x4 acc[2][4] = {};

  for (int k0 = 0; k0 < 1024; k0 += 64) {
#pragma unroll
    for (int i = 0; i < 4; ++i) {
      int c = i * 256 + tid;
      gl2lds16(cb + (m0 + (c >> 3)) * 1024 + k0 + (c & 7) * 8, As + c * 8);
    }
#pragma unroll
    for (int i = 0; i < 2; ++i) {
      int c = i * 256 + tid;
      gl2lds16(wob + (n0 + (c >> 3)) * 1024 + k0 + (c & 7) * 8, Bs + c * 8);
    }
    __syncthreads();
#pragma unroll
    for (int kk = 0; kk < 2; ++kk) {
      short8 af[2], bf[4];
#pragma unroll
      for (int mb = 0; mb < 2; ++mb)
        af[mb] = *(const short8*)(As + (wid * 32 + mb * 16 + l15) * 64 + kk * 32 + lg * 8);
#pragma unroll
      for (int nb = 0; nb < 4; ++nb)
        bf[nb] = *(const short8*)(Bs + (nb * 16 + l15) * 64 + kk * 32 + lg * 8);
#pragma unroll
      for (int mb = 0; mb < 2; ++mb)
#pragma unroll
        for (int nb = 0; nb < 4; ++nb)
          acc[mb][nb] = __builtin_amdgcn_mfma_f32_16x16x32_bf16(af[mb], bf[nb], acc[mb][nb], 0, 0, 0);
    }
    __syncthreads();
  }

#pragma unroll
  for (int mb = 0; mb < 2; ++mb)
#pragma unroll
    for (int nb = 0; nb < 4; ++nb)
#pragma unroll
      for (int r = 0; r < 4; ++r) {
        int m = m0 + wid * 32 + mb * 16 + lg * 4 + r;
        int n = n0 + nb * 16 + l15;
        out[m * 1024 + n] = acc[mb][nb][r] + bo[n];
      }
}

// --------------------------------------------------------------------- launch
extern "C" void kernel_launch(void* const* d_in, const int* in_sizes, int n_in,
                              void* d_out, int out_size, void* d_ws, size_t ws_size,
                              hipStream_t stream) {
  const float* x  = (const float*)d_in[0];
  const float* wq = (const float*)d_in[1];
  const float* bq = (const float*)d_in[2];
  const float* wk = (const float*)d_in[3];
  const float* bk = (const float*)d_in[4];
  const float* wv = (const float*)d_in[5];
  const float* bv = (const float*)d_in[6];
  const float* wo = (const float*)d_in[7];
  const float* bo = (const float*)d_in[8];

  if (ws_size < (size_t)24 * 1024 * 1024 * 2) return;
  u16* xb   = (u16*)d_ws;
  u16* wqb  = xb  + (4u << 20);
  u16* wkb  = wqb + (1u << 20);
  u16* wvb  = wkb + (1u << 20);
  u16* wob  = wvb + (1u << 20);
  u16* qb   = wob + (1u << 20);
  u16* kb   = qb  + (4u << 20);
  u16* vtb  = kb  + (4u << 20);   // V^T [B,NH,D,Sperm] (sigma-permuted keys)
  u16* ctxb = vtb + (4u << 20);

  cvt_kernel<<<dim3(512, 8, 1), 256, 0, stream>>>(x, wq, wk, wv, wo, xb, wqb, wkb, wvb, wob);
  gemm_qkv<<<dim3(8, 32, 3), 256, 0, stream>>>(xb, wqb, wkb, wvb, bq, bk, bv, qb, kb, vtb);
  attn_kernel<<<dim3(16, 16, 2), 256, 0, stream>>>(qb, kb, vtb, ctxb);
  gemm_out<<<dim3(16, 32, 1), 256, 0, stream>>>(ctxb, wob, bo, (float*)d_out);
}

// Round 6
// 205.630 us; speedup vs baseline: 1.3645x; 1.3645x over previous
//
#include <hip/hip_runtime.h>
#include <cstdint>

typedef unsigned short u16;
typedef __attribute__((ext_vector_type(8))) short short8;
typedef __attribute__((ext_vector_type(4))) float f32x4;

#if __has_builtin(__builtin_amdgcn_exp2f)
#define EXP2F(x) __builtin_amdgcn_exp2f(x)
#else
#define EXP2F(x) exp2f(x)
#endif

// fp32 -> bf16 bits, round-to-nearest-even
__device__ inline u16 f2bf(float f) {
  union { float f; unsigned u; } v; v.f = f;
  unsigned u = v.u;
  return (u16)((u + 0x7fffu + ((u >> 16) & 1u)) >> 16);
}

// pack two fp32 -> bf16x2 (a -> low); round-half-up (P>0 only, 1ulp vs RNE)
__device__ inline unsigned pk2bf_fast(float a, float b) {
  union { float f; unsigned u; } ua, ub; ua.f = a; ub.f = b;
  return __builtin_amdgcn_perm(ub.u + 0x8000u, ua.u + 0x8000u, 0x07060302u);
}

// ---------------------------------------------------------------- cvt kernel
__global__ __launch_bounds__(256) void cvt_kernel(
    const float* __restrict__ x,
    const float* __restrict__ wq, const float* __restrict__ wk,
    const float* __restrict__ wv, const float* __restrict__ wo,
    u16* __restrict__ xb, u16* __restrict__ wqb, u16* __restrict__ wkb,
    u16* __restrict__ wvb, u16* __restrict__ wob) {
  const int y = blockIdx.y;
  const int Q = 1 << 20;
  const float* src;
  u16* dst;
  if (y < 4)       { src = x + y * Q; dst = xb + y * Q; }
  else if (y == 4) { src = wq; dst = wqb; }
  else if (y == 5) { src = wk; dst = wkb; }
  else if (y == 6) { src = wv; dst = wvb; }
  else             { src = wo; dst = wob; }
  const int i = (blockIdx.x * 256 + threadIdx.x) * 8;
  float4 a = *(const float4*)(src + i);
  float4 b = *(const float4*)(src + i + 4);
  short8 o;
  o[0] = (short)f2bf(a.x); o[1] = (short)f2bf(a.y);
  o[2] = (short)f2bf(a.z); o[3] = (short)f2bf(a.w);
  o[4] = (short)f2bf(b.x); o[5] = (short)f2bf(b.y);
  o[6] = (short)f2bf(b.z); o[7] = (short)f2bf(b.w);
  *(short8*)(dst + i) = o;
}

// ------------------------------------------------------------ QKV projection
// NT GEMM, M=4096 N=1024 K=1024; grid (8, 32, 3). Register-staged pipeline:
// global->reg loads for iter k+1 issued between staging and compute of k, so
// the vmcnt wait lands one full compute-phase after issue (no barrier drain).
// z==0/1 -> Q/K in [B,NH,S,D]; z==2 -> V^T [B,NH,D,Sperm],
// sigma(s) = (s&15)*4 + ((s>>4)&3).
__global__ __launch_bounds__(256) void gemm_qkv(
    const u16* __restrict__ xb,
    const u16* __restrict__ wqb, const u16* __restrict__ wkb, const u16* __restrict__ wvb,
    const float* __restrict__ bq, const float* __restrict__ bk, const float* __restrict__ bv,
    u16* __restrict__ qo, u16* __restrict__ ko, u16* __restrict__ vto) {
  const int z = blockIdx.z;
  const u16* W = (z == 0) ? wqb : (z == 1) ? wkb : wvb;
  const float* bias = (z == 0) ? bq : (z == 1) ? bk : bv;

  __shared__ u16 smem[18432];
  u16* As = smem;
  u16* Bs = smem + 8192;
  const int tid = threadIdx.x, lane = tid & 63;
  const int wid = tid >> 6, wm = wid >> 1, wn = wid & 1;
  const int l15 = lane & 15, lg = lane >> 4;
  const int m0 = blockIdx.y * 128, n0 = blockIdx.x * 128;

  f32x4 acc[4][4] = {};
  short8 areg[4], breg[4];

#pragma unroll
  for (int i = 0; i < 4; ++i) {
    int c = i * 256 + tid;
    areg[i] = *(const short8*)(xb + (m0 + (c >> 3)) * 1024 + (c & 7) * 8);
    breg[i] = *(const short8*)(W  + (n0 + (c >> 3)) * 1024 + (c & 7) * 8);
  }

  for (int k0 = 0; k0 < 1024; k0 += 64) {
    __syncthreads();  // prior iteration done reading As/Bs
#pragma unroll
    for (int i = 0; i < 4; ++i) {
      int c = i * 256 + tid;
      *(short8*)(As + c * 8) = areg[i];
      *(short8*)(Bs + c * 8) = breg[i];
    }
    if (k0 < 960) {
#pragma unroll
      for (int i = 0; i < 4; ++i) {
        int c = i * 256 + tid;
        areg[i] = *(const short8*)(xb + (m0 + (c >> 3)) * 1024 + k0 + 64 + (c & 7) * 8);
        breg[i] = *(const short8*)(W  + (n0 + (c >> 3)) * 1024 + k0 + 64 + (c & 7) * 8);
      }
    }
    __syncthreads();  // staging visible
#pragma unroll
    for (int kk = 0; kk < 2; ++kk) {
      short8 af[4], bf[4];
#pragma unroll
      for (int mb = 0; mb < 4; ++mb)
        af[mb] = *(const short8*)(As + (wm * 64 + mb * 16 + l15) * 64 + kk * 32 + lg * 8);
#pragma unroll
      for (int nb = 0; nb < 4; ++nb)
        bf[nb] = *(const short8*)(Bs + (wn * 64 + nb * 16 + l15) * 64 + kk * 32 + lg * 8);
#pragma unroll
      for (int mb = 0; mb < 4; ++mb)
#pragma unroll
        for (int nb = 0; nb < 4; ++nb)
          acc[mb][nb] = __builtin_amdgcn_mfma_f32_16x16x32_bf16(af[mb], bf[nb], acc[mb][nb], 0, 0, 0);
    }
  }

  if (z < 2) {
    u16* out = (z == 0) ? qo : ko;
#pragma unroll
    for (int mb = 0; mb < 4; ++mb)
#pragma unroll
      for (int nb = 0; nb < 4; ++nb)
#pragma unroll
        for (int r = 0; r < 4; ++r) {
          int m = m0 + wm * 64 + mb * 16 + lg * 4 + r;  // b*2048 + s
          int n = n0 + wn * 64 + nb * 16 + l15;         // h*64 + d
          float v = acc[mb][nb][r] + bias[n];
          int b = m >> 11, s = m & 2047, h = n >> 6, d = n & 63;
          out[((b * 16 + h) * 2048 + s) * 64 + d] = f2bf(v);
        }
  } else {
    __syncthreads();  // all waves done with As/Bs before wbuf reuse
    u16* wbuf = smem + wid * 4608;  // 64 x 72
#pragma unroll
    for (int mb = 0; mb < 4; ++mb)
#pragma unroll
      for (int nb = 0; nb < 4; ++nb) {
        int n = n0 + wn * 64 + nb * 16 + l15;
        float bn = bias[n];
        int dl = nb * 16 + l15;
#pragma unroll
        for (int r = 0; r < 4; ++r) {
          int sig = (lg * 4 + r) * 4 + mb;  // sigma of s_local = mb*16+lg*4+r
          wbuf[dl * 72 + sig] = f2bf(acc[mb][nb][r] + bn);
        }
      }
    int h_w = (n0 >> 6) + wn;
    int mbase = m0 + wm * 64;
    int b = mbase >> 11, sb = mbase & 2047;
#pragma unroll
    for (int i = 0; i < 8; ++i) {
      int dl = (lane >> 3) + 8 * i;
      int c = lane & 7;
      short8 vv = *(const short8*)(wbuf + dl * 72 + c * 8);
      *(short8*)(vto + ((b * 16 + h_w) * 64 + dl) * 2048 + sb + c * 8) = vv;
    }
  }
}

// ---------------------------------------------------------------- attention
// flash-style, Q-tile 128 x K-tile 64, grid (16,16,2), 256 thr. K/V staged
// through LDS with register-pipelined loads (kt+1 regs loaded right after
// staging kt -> vmcnt wait hidden under full compute phase). Q fragments
// direct from global (once). Fixed-max softmax P = exp2(s*log2e/8 - 4);
// row-sum via ones-register B operand (l replicated across cols, no shfl).
__global__ __launch_bounds__(256, 2) void attn_kernel(
    const u16* __restrict__ qg, const u16* __restrict__ kg,
    const u16* __restrict__ vtg, u16* __restrict__ ctxg) {
  const int h = blockIdx.x, qt = blockIdx.y, b = blockIdx.z;
  const int bh = b * 16 + h;
  const u16* Qg = qg + (bh * 2048 + qt * 128) * 64;
  const u16* Kg = kg + bh * 2048 * 64;
  const u16* Vg = vtg + bh * 64 * 2048;

  __shared__ u16 SP[128 * 72];   // P only; wave-private 32-row strips
  __shared__ u16 Ks[64 * 72];
  __shared__ u16 Vts[64 * 72];

  const int tid = threadIdx.x, lane = tid & 63, wid = tid >> 6;
  const int l15 = lane & 15, lg = lane >> 4;
  const int row0 = wid * 32;

  // Q fragments direct from global (reused all 32 kt)
  short8 qf[2][2];
#pragma unroll
  for (int mb = 0; mb < 2; ++mb)
#pragma unroll
    for (int kk = 0; kk < 2; ++kk)
      qf[mb][kk] = *(const short8*)(Qg + (row0 + mb * 16 + l15) * 64 + kk * 32 + lg * 8);

  short8 ones8;
#pragma unroll
  for (int j = 0; j < 8; ++j) ones8[j] = (short)0x3F80;  // bf16 1.0

  // prefetch kt=0 K/V into registers
  short8 kreg[2], vreg[2];
#pragma unroll
  for (int i = 0; i < 2; ++i) {
    int c = i * 256 + tid;
    kreg[i] = *(const short8*)(Kg + c * 8);
    vreg[i] = *(const short8*)(Vg + (c >> 3) * 2048 + (c & 7) * 8);
  }

  f32x4 acc[2][5] = {};  // nd 0..3 = ctx, nd 4 = row-sum
  const float cexp = 0.18033688011112042f;  // log2(e)/8

  for (int kt = 0; kt < 32; ++kt) {
    __syncthreads();  // prior iteration done reading Ks/Vts
#pragma unroll
    for (int i = 0; i < 2; ++i) {
      int c = i * 256 + tid;
      *(short8*)(Ks  + (c >> 3) * 72 + (c & 7) * 8) = kreg[i];
      *(short8*)(Vts + (c >> 3) * 72 + (c & 7) * 8) = vreg[i];
    }
    // issue loads for kt+1 now; they have the whole compute phase to land
    {
      const int ktn = (kt + 1 < 32) ? kt + 1 : 0;  // last prefetch discarded
#pragma unroll
      for (int i = 0; i < 2; ++i) {
        int c = i * 256 + tid;
        kreg[i] = *(const short8*)(Kg + ktn * 4096 + c * 8);
        vreg[i] = *(const short8*)(Vg + (c >> 3) * 2048 + ktn * 64 + (c & 7) * 8);
      }
    }
    __syncthreads();  // staging visible

    // S = Q K^T (raw scores; col of tile nb = key nb*16+l15)
    f32x4 sc[2][4] = {};
#pragma unroll
    for (int kk = 0; kk < 2; ++kk) {
      short8 bfr[4];
#pragma unroll
      for (int nb = 0; nb < 4; ++nb)
        bfr[nb] = *(const short8*)(Ks + (nb * 16 + l15) * 72 + kk * 32 + lg * 8);
#pragma unroll
      for (int mb = 0; mb < 2; ++mb)
#pragma unroll
        for (int nb = 0; nb < 4; ++nb)
          sc[mb][nb] = __builtin_amdgcn_mfma_f32_16x16x32_bf16(qf[mb][kk], bfr[nb], sc[mb][nb], 0, 0, 0);
    }

    // P = exp2(s*c - 4); sigma(key = nb*16+l15) = l15*4+nb -> one b64 per row
#pragma unroll
    for (int mb = 0; mb < 2; ++mb)
#pragma unroll
      for (int r = 0; r < 4; ++r) {
        float p0 = EXP2F(fmaf(sc[mb][0][r], cexp, -4.0f));
        float p1 = EXP2F(fmaf(sc[mb][1][r], cexp, -4.0f));
        float p2 = EXP2F(fmaf(sc[mb][2][r], cexp, -4.0f));
        float p3 = EXP2F(fmaf(sc[mb][3][r], cexp, -4.0f));
        uint2 u;
        u.x = pk2bf_fast(p0, p1);
        u.y = pk2bf_fast(p2, p3);
        *(uint2*)(SP + (row0 + mb * 16 + lg * 4 + r) * 72 + l15 * 4) = u;
      }

    // ctx += P @ [V | 1]  (same-wave LDS write->read, in-order)
#pragma unroll
    for (int kk = 0; kk < 2; ++kk) {
      short8 pa[2], vb[4];
#pragma unroll
      for (int mb = 0; mb < 2; ++mb)
        pa[mb] = *(const short8*)(SP + (row0 + mb * 16 + l15) * 72 + kk * 32 + lg * 8);
#pragma unroll
      for (int nd = 0; nd < 4; ++nd)
        vb[nd] = *(const short8*)(Vts + (nd * 16 + l15) * 72 + kk * 32 + lg * 8);
#pragma unroll
      for (int mb = 0; mb < 2; ++mb) {
#pragma unroll
        for (int nd = 0; nd < 4; ++nd)
          acc[mb][nd] = __builtin_amdgcn_mfma_f32_16x16x32_bf16(pa[mb], vb[nd], acc[mb][nd], 0, 0, 0);
        acc[mb][4] = __builtin_amdgcn_mfma_f32_16x16x32_bf16(pa[mb], ones8, acc[mb][4], 0, 0, 0);
      }
    }
  }

  // epilogue: l = acc[mb][4][r] (replicated across cols)
#pragma unroll
  for (int mb = 0; mb < 2; ++mb)
#pragma unroll
    for (int r = 0; r < 4; ++r) {
      float inv = 1.0f / acc[mb][4][r];
      int s = qt * 128 + row0 + mb * 16 + lg * 4 + r;
      u16* dst = ctxg + (b * 2048 + s) * 1024 + h * 64;
#pragma unroll
      for (int nd = 0; nd < 4; ++nd)
        dst[nd * 16 + l15] = f2bf(acc[mb][nd][r] * inv);
    }
}

// ------------------------------------------------------------ out projection
// 128m x 64n tiles, grid (16, 32) = 512 blocks; register-staged pipeline.
__global__ __launch_bounds__(256) void gemm_out(
    const u16* __restrict__ cb, const u16* __restrict__ wob,
    const float* __restrict__ bo, float* __restrict__ out) {
  __shared__ u16 As[128 * 64];
  __shared__ u16 Bs[64 * 64];
  const int tid = threadIdx.x, lane = tid & 63;
  const int wid = tid >> 6;
  const int l15 = lane & 15, lg = lane >> 4;
  const int m0 = blockIdx.y * 128, n0 = blockIdx.x * 64;

  f32x4 acc[2][4] = {};
  short8 areg[4], breg[2];

#pragma unroll
  for (int i = 0; i < 4; ++i) {
    int c = i * 256 + tid;
    areg[i] = *(const short8*)(cb + (m0 + (c >> 3)) * 1024 + (c & 7) * 8);
  }
#pragma unroll
  for (int i = 0; i < 2; ++i) {
    int c = i * 256 + tid;
    breg[i] = *(const short8*)(wob + (n0 + (c >> 3)) * 1024 + (c & 7) * 8);
  }

  for (int k0 = 0; k0 < 1024; k0 += 64) {
    __syncthreads();
#pragma unroll
    for (int i = 0; i < 4; ++i) {
      int c = i * 256 + tid;
      *(short8*)(As + c * 8) = areg[i];
    }
#pragma unroll
    for (int i = 0; i < 2; ++i) {
      int c = i * 256 + tid;
      *(short8*)(Bs + c * 8) = breg[i];
    }
    if (k0 < 960) {
#pragma unroll
      for (int i = 0; i < 4; ++i) {
        int c = i * 256 + tid;
        areg[i] = *(const short8*)(cb + (m0 + (c >> 3)) * 1024 + k0 + 64 + (c & 7) * 8);
      }
#pragma unroll
      for (int i = 0; i < 2; ++i) {
        int c = i * 256 + tid;
        breg[i] = *(const short8*)(wob + (n0 + (c >> 3)) * 1024 + k0 + 64 + (c & 7) * 8);
      }
    }
    __syncthreads();
#pragma unroll
    for (int kk = 0; kk < 2; ++kk) {
      short8 af[2], bf[4];
#pragma unroll
      for (int mb = 0; mb < 2; ++mb)
        af[mb] = *(const short8*)(As + (wid * 32 + mb * 16 + l15) * 64 + kk * 32 + lg * 8);
#pragma unroll
      for (int nb = 0; nb < 4; ++nb)
        bf[nb] = *(const short8*)(Bs + (nb * 16 + l15) * 64 + kk * 32 + lg * 8);
#pragma unroll
      for (int mb = 0; mb < 2; ++mb)
#pragma unroll
        for (int nb = 0; nb < 4; ++nb)
          acc[mb][nb] = __builtin_amdgcn_mfma_f32_16x16x32_bf16(af[mb], bf[nb], acc[mb][nb], 0, 0, 0);
    }
  }

#pragma unroll
  for (int mb = 0; mb < 2; ++mb)
#pragma unroll
    for (int nb = 0; nb < 4; ++nb)
#pragma unroll
      for (int r = 0; r < 4; ++r) {
        int m = m0 + wid * 32 + mb * 16 + lg * 4 + r;
        int n = n0 + nb * 16 + l15;
        out[m * 1024 + n] = acc[mb][nb][r] + bo[n];
      }
}

// --------------------------------------------------------------------- launch
extern "C" void kernel_launch(void* const* d_in, const int* in_sizes, int n_in,
                              void* d_out, int out_size, void* d_ws, size_t ws_size,
                              hipStream_t stream) {
  const float* x  = (const float*)d_in[0];
  const float* wq = (const float*)d_in[1];
  const float* bq = (const float*)d_in[2];
  const float* wk = (const float*)d_in[3];
  const float* bk = (const float*)d_in[4];
  const float* wv = (const float*)d_in[5];
  const float* bv = (const float*)d_in[6];
  const float* wo = (const float*)d_in[7];
  const float* bo = (const float*)d_in[8];

  if (ws_size < (size_t)24 * 1024 * 1024 * 2) return;
  u16* xb   = (u16*)d_ws;
  u16* wqb  = xb  + (4u << 20);
  u16* wkb  = wqb + (1u << 20);
  u16* wvb  = wkb + (1u << 20);
  u16* wob  = wvb + (1u << 20);
  u16* qb   = wob + (1u << 20);
  u16* kb   = qb  + (4u << 20);
  u16* vtb  = kb  + (4u << 20);   // V^T [B,NH,D,Sperm] (sigma-permuted keys)
  u16* ctxb = vtb + (4u << 20);

  cvt_kernel<<<dim3(512, 8, 1), 256, 0, stream>>>(x, wq, wk, wv, wo, xb, wqb, wkb, wvb, wob);
  gemm_qkv<<<dim3(8, 32, 3), 256, 0, stream>>>(xb, wqb, wkb, wvb, bq, bk, bv, qb, kb, vtb);
  attn_kernel<<<dim3(16, 16, 2), 256, 0, stream>>>(qb, kb, vtb, ctxb);
  gemm_out<<<dim3(16, 32, 1), 256, 0, stream>>>(ctxb, wob, bo, (float*)d_out);
}

// Round 7
// 190.034 us; speedup vs baseline: 1.4765x; 1.0821x over previous
//
#include <hip/hip_runtime.h>
#include <cstdint>

typedef unsigned short u16;
typedef __attribute__((ext_vector_type(8))) short short8;
typedef __attribute__((ext_vector_type(4))) float f32x4;

#if __has_builtin(__builtin_amdgcn_exp2f)
#define EXP2F(x) __builtin_amdgcn_exp2f(x)
#else
#define EXP2F(x) exp2f(x)
#endif

// fp32 -> bf16 bits, round-to-nearest-even
__device__ inline u16 f2bf(float f) {
  union { float f; unsigned u; } v; v.f = f;
  unsigned u = v.u;
  return (u16)((u + 0x7fffu + ((u >> 16) & 1u)) >> 16);
}

// pack two fp32 -> bf16x2 (a -> low); round-half-up (P>0 only, 1ulp vs RNE)
__device__ inline unsigned pk2bf_fast(float a, float b) {
  union { float f; unsigned u; } ua, ub; ua.f = a; ub.f = b;
  return __builtin_amdgcn_perm(ub.u + 0x8000u, ua.u + 0x8000u, 0x07060302u);
}

// async global -> LDS, 16B per lane (contiguous landing order only)
__device__ inline void gl2lds16(const void* g, void* l) {
  __builtin_amdgcn_global_load_lds(
      (const __attribute__((address_space(1))) unsigned int*)(unsigned long long)(uintptr_t)g,
      (__attribute__((address_space(3))) unsigned int*)(unsigned int)(uintptr_t)l,
      16, 0, 0);
}

// XOR chunk swizzle: within each 64-elem K-slice of a row, 16B chunk c of row
// r is stored at position c ^ (r & 7). gl2lds staging copies slices verbatim;
// fragment reads at chunk' = (kk*4+lg) ^ (l15&7) are then phase-conflict-free
// (8 consecutive lanes -> 8 distinct chunk columns) with no padding.

// ---------------------------------------------------------------- cvt kernel
// converts fp32->bf16 AND stores chunk-swizzled (row = i>>10, all matrices
// have 1024-elem rows).
__global__ __launch_bounds__(256) void cvt_kernel(
    const float* __restrict__ x,
    const float* __restrict__ wq, const float* __restrict__ wk,
    const float* __restrict__ wv, const float* __restrict__ wo,
    u16* __restrict__ xb, u16* __restrict__ wqb, u16* __restrict__ wkb,
    u16* __restrict__ wvb, u16* __restrict__ wob) {
  const int y = blockIdx.y;
  const int Q = 1 << 20;
  const float* src;
  u16* dst;
  if (y < 4)       { src = x + y * Q; dst = xb + y * Q; }
  else if (y == 4) { src = wq; dst = wqb; }
  else if (y == 5) { src = wk; dst = wkb; }
  else if (y == 6) { src = wv; dst = wvb; }
  else             { src = wo; dst = wob; }
  const int i = (blockIdx.x * 256 + threadIdx.x) * 8;
  float4 a = *(const float4*)(src + i);
  float4 b = *(const float4*)(src + i + 4);
  short8 o;
  o[0] = (short)f2bf(a.x); o[1] = (short)f2bf(a.y);
  o[2] = (short)f2bf(a.z); o[3] = (short)f2bf(a.w);
  o[4] = (short)f2bf(b.x); o[5] = (short)f2bf(b.y);
  o[6] = (short)f2bf(b.z); o[7] = (short)f2bf(b.w);
  const int j = (i & ~63) | (((((i >> 3) & 7) ^ ((i >> 10) & 7))) << 3);
  *(short8*)(dst + j) = o;
}

// ------------------------------------------------------------ QKV projection
// NT GEMM, M=4096 N=1024 K=1024; grid (8, 32, 3). Double-buffered gl2lds
// staging, ONE barrier per K-iter (loads for k+1 issued right after the
// barrier -> full compute phase to land before next barrier's vmcnt drain).
// z==0 -> Q [B,NH,S,D] plain; z==1 -> K [B,NH,S,D] chunk-swizzled by s&7;
// z==2 -> V^T [B,NH,D,Sperm] (sigma(s)=(s&15)*4+((s>>4)&3)), chunk-swizzled
// by d&7.
__global__ __launch_bounds__(256) void gemm_qkv(
    const u16* __restrict__ xb,
    const u16* __restrict__ wqb, const u16* __restrict__ wkb, const u16* __restrict__ wvb,
    const float* __restrict__ bq, const float* __restrict__ bk, const float* __restrict__ bv,
    u16* __restrict__ qo, u16* __restrict__ ko, u16* __restrict__ vto) {
  const int z = blockIdx.z;
  const u16* W = (z == 0) ? wqb : (z == 1) ? wkb : wvb;
  const float* bias = (z == 0) ? bq : (z == 1) ? bk : bv;

  __shared__ u16 smem[32768];           // As[2][8192] | Bs[2][8192] = 64 KB
  u16* As = smem;
  u16* Bs = smem + 16384;
  const int tid = threadIdx.x, lane = tid & 63;
  const int wid = tid >> 6, wm = wid >> 1, wn = wid & 1;
  const int l15 = lane & 15, lg = lane >> 4;
  const int m0 = blockIdx.y * 128, n0 = blockIdx.x * 128;
  const int sw = ((l15 & 7) << 3);      // XOR term (in elems) for frag reads

  f32x4 acc[4][4] = {};

  // prologue: stage k0=0 into buffer 0
#pragma unroll
  for (int i = 0; i < 4; ++i) {
    int c = i * 256 + tid;
    gl2lds16(xb + (m0 + (c >> 3)) * 1024 + (c & 7) * 8, As + c * 8);
    gl2lds16(W  + (n0 + (c >> 3)) * 1024 + (c & 7) * 8, Bs + c * 8);
  }

  for (int k0 = 0; k0 < 1024; k0 += 64) {
    const int p = (k0 >> 6) & 1;
    __syncthreads();  // drains vmcnt -> buf p ready; all waves done with 1-p
    if (k0 < 960) {
      u16* An = As + (1 - p) * 8192;
      u16* Bn = Bs + (1 - p) * 8192;
#pragma unroll
      for (int i = 0; i < 4; ++i) {
        int c = i * 256 + tid;
        gl2lds16(xb + (m0 + (c >> 3)) * 1024 + k0 + 64 + (c & 7) * 8, An + c * 8);
        gl2lds16(W  + (n0 + (c >> 3)) * 1024 + k0 + 64 + (c & 7) * 8, Bn + c * 8);
      }
    }
    const u16* Ap = As + p * 8192;
    const u16* Bp = Bs + p * 8192;
#pragma unroll
    for (int kk = 0; kk < 2; ++kk) {
      short8 af[4], bf[4];
#pragma unroll
      for (int mb = 0; mb < 4; ++mb)
        af[mb] = *(const short8*)(Ap + (wm * 64 + mb * 16 + l15) * 64 + ((((kk * 4 + lg) << 3) ^ sw)));
#pragma unroll
      for (int nb = 0; nb < 4; ++nb)
        bf[nb] = *(const short8*)(Bp + (wn * 64 + nb * 16 + l15) * 64 + ((((kk * 4 + lg) << 3) ^ sw)));
#pragma unroll
      for (int mb = 0; mb < 4; ++mb)
#pragma unroll
        for (int nb = 0; nb < 4; ++nb)
          acc[mb][nb] = __builtin_amdgcn_mfma_f32_16x16x32_bf16(af[mb], bf[nb], acc[mb][nb], 0, 0, 0);
    }
  }

  if (z < 2) {
    u16* out = (z == 0) ? qo : ko;
#pragma unroll
    for (int mb = 0; mb < 4; ++mb)
#pragma unroll
      for (int nb = 0; nb < 4; ++nb)
#pragma unroll
        for (int r = 0; r < 4; ++r) {
          int m = m0 + wm * 64 + mb * 16 + lg * 4 + r;  // b*2048 + s
          int n = n0 + wn * 64 + nb * 16 + l15;         // h*64 + d
          float v = acc[mb][nb][r] + bias[n];
          int b = m >> 11, s = m & 2047, hh = n >> 6, d = n & 63;
          int dcol = (z == 0) ? d : ((((d >> 3) ^ (s & 7)) << 3) | (d & 7));
          out[((b * 16 + hh) * 2048 + s) * 64 + dcol] = f2bf(v);
        }
  } else {
    __syncthreads();  // all waves done with As/Bs before wbuf reuse
    u16* wbuf = smem + wid * 4608;  // 64 x 72 per wave
#pragma unroll
    for (int mb = 0; mb < 4; ++mb)
#pragma unroll
      for (int nb = 0; nb < 4; ++nb) {
        int n = n0 + wn * 64 + nb * 16 + l15;
        float bn = bias[n];
        int dl = nb * 16 + l15;
#pragma unroll
        for (int r = 0; r < 4; ++r) {
          int sig = (lg * 4 + r) * 4 + mb;  // sigma of s_local = mb*16+lg*4+r
          wbuf[dl * 72 + sig] = f2bf(acc[mb][nb][r] + bn);
        }
      }
    int h_w = (n0 >> 6) + wn;
    int mbase = m0 + wm * 64;
    int b = mbase >> 11, sb = mbase & 2047;
#pragma unroll
    for (int i = 0; i < 8; ++i) {
      int dl = (lane >> 3) + 8 * i;
      int c = lane & 7;
      short8 vv = *(const short8*)(wbuf + dl * 72 + c * 8);
      int cs = c ^ (dl & 7);  // chunk swizzle by d&7
      *(short8*)(vto + ((b * 16 + h_w) * 64 + dl) * 2048 + sb + cs * 8) = vv;
    }
  }
}

// ---------------------------------------------------------------- attention
// flash-style, Q-tile 128 x K-tile 64, grid (16,16,2), 256 thr. K/V^T staged
// via gl2lds into double-buffered LDS, ONE barrier per kt (prefetch issued
// right after the barrier -> full phase before the next drain). Fragment
// reads conflict-free via baked chunk swizzle. Q fragments direct from
// global. Fixed-max softmax P = exp2(s*log2e/8 - 4); row-sum via
// ones-register B operand.
__global__ __launch_bounds__(256, 2) void attn_kernel(
    const u16* __restrict__ qg, const u16* __restrict__ kg,
    const u16* __restrict__ vtg, u16* __restrict__ ctxg) {
  const int h = blockIdx.x, qt = blockIdx.y, b = blockIdx.z;
  const int bh = b * 16 + h;
  const u16* Qg = qg + (bh * 2048 + qt * 128) * 64;
  const u16* Kg = kg + bh * 2048 * 64;
  const u16* Vg = vtg + bh * 64 * 2048;

  __shared__ u16 SP[128 * 72];   // P round-trip; wave-private 32-row strips
  __shared__ u16 KV[2][8192];    // [p][0:4096)=K tile, [p][4096:8192)=V^T tile

  const int tid = threadIdx.x, lane = tid & 63, wid = tid >> 6;
  const int l15 = lane & 15, lg = lane >> 4;
  const int row0 = wid * 32;
  const int sw = ((l15 & 7) << 3);

  // Q fragments direct from global (plain layout, reused all 32 kt)
  short8 qf[2][2];
#pragma unroll
  for (int mb = 0; mb < 2; ++mb)
#pragma unroll
    for (int kk = 0; kk < 2; ++kk)
      qf[mb][kk] = *(const short8*)(Qg + (row0 + mb * 16 + l15) * 64 + kk * 32 + lg * 8);

  short8 ones8;
#pragma unroll
  for (int j = 0; j < 8; ++j) ones8[j] = (short)0x3F80;  // bf16 1.0

  // prologue: stage kt=0 into buffer 0
#pragma unroll
  for (int i = 0; i < 2; ++i) {
    int c = i * 256 + tid;
    gl2lds16(Kg + c * 8, &KV[0][c * 8]);
    gl2lds16(Vg + (c >> 3) * 2048 + (c & 7) * 8, &KV[0][4096 + c * 8]);
  }

  f32x4 acc[2][5] = {};  // nd 0..3 = ctx, nd 4 = row-sum
  const float cexp = 0.18033688011112042f;  // log2(e)/8

  for (int kt = 0; kt < 32; ++kt) {
    const int p = kt & 1;
    __syncthreads();  // drains vmcnt -> buf p ready; all waves done with 1-p
    if (kt < 31) {
#pragma unroll
      for (int i = 0; i < 2; ++i) {
        int c = i * 256 + tid;
        gl2lds16(Kg + (kt + 1) * 4096 + c * 8, &KV[1 - p][c * 8]);
        gl2lds16(Vg + (c >> 3) * 2048 + (kt + 1) * 64 + (c & 7) * 8, &KV[1 - p][4096 + c * 8]);
      }
    }
    const u16* Ks = &KV[p][0];
    const u16* Vts = &KV[p][4096];

    // S = Q K^T
    f32x4 sc[2][4] = {};
#pragma unroll
    for (int kk = 0; kk < 2; ++kk) {
      short8 bfr[4];
#pragma unroll
      for (int nb = 0; nb < 4; ++nb)
        bfr[nb] = *(const short8*)(Ks + (nb * 16 + l15) * 64 + ((((kk * 4 + lg) << 3)) ^ sw));
#pragma unroll
      for (int mb = 0; mb < 2; ++mb)
#pragma unroll
        for (int nb = 0; nb < 4; ++nb)
          sc[mb][nb] = __builtin_amdgcn_mfma_f32_16x16x32_bf16(qf[mb][kk], bfr[nb], sc[mb][nb], 0, 0, 0);
    }

    // P = exp2(s*c - 4); sigma(key = nb*16+l15) = l15*4+nb -> one b64 per row
#pragma unroll
    for (int mb = 0; mb < 2; ++mb)
#pragma unroll
      for (int r = 0; r < 4; ++r) {
        float p0 = EXP2F(fmaf(sc[mb][0][r], cexp, -4.0f));
        float p1 = EXP2F(fmaf(sc[mb][1][r], cexp, -4.0f));
        float p2 = EXP2F(fmaf(sc[mb][2][r], cexp, -4.0f));
        float p3 = EXP2F(fmaf(sc[mb][3][r], cexp, -4.0f));
        uint2 u;
        u.x = pk2bf_fast(p0, p1);
        u.y = pk2bf_fast(p2, p3);
        *(uint2*)(SP + (row0 + mb * 16 + lg * 4 + r) * 72 + l15 * 4) = u;
      }

    // ctx += P @ [V | 1]  (same-wave LDS write->read, in-order)
#pragma unroll
    for (int kk = 0; kk < 2; ++kk) {
      short8 pa[2], vb[4];
#pragma unroll
      for (int mb = 0; mb < 2; ++mb)
        pa[mb] = *(const short8*)(SP + (row0 + mb * 16 + l15) * 72 + kk * 32 + lg * 8);
#pragma unroll
      for (int nd = 0; nd < 4; ++nd)
        vb[nd] = *(const short8*)(Vts + (nd * 16 + l15) * 64 + ((((kk * 4 + lg) << 3)) ^ sw));
#pragma unroll
      for (int mb = 0; mb < 2; ++mb) {
#pragma unroll
        for (int nd = 0; nd < 4; ++nd)
          acc[mb][nd] = __builtin_amdgcn_mfma_f32_16x16x32_bf16(pa[mb], vb[nd], acc[mb][nd], 0, 0, 0);
        acc[mb][4] = __builtin_amdgcn_mfma_f32_16x16x32_bf16(pa[mb], ones8, acc[mb][4], 0, 0, 0);
      }
    }
  }

  // epilogue: l = acc[mb][4][r] (replicated across cols); ctx stored
  // chunk-swizzled by s&7 for gemm_out's fragment reads.
#pragma unroll
  for (int mb = 0; mb < 2; ++mb)
#pragma unroll
    for (int r = 0; r < 4; ++r) {
      float inv = 1.0f / acc[mb][4][r];
      int s = qt * 128 + row0 + mb * 16 + lg * 4 + r;
      int s7 = s & 7;
      u16* dst = ctxg + (b * 2048 + s) * 1024 + h * 64;
#pragma unroll
      for (int nd = 0; nd < 4; ++nd) {
        int d = nd * 16 + l15;
        int dcol = (((d >> 3) ^ s7) << 3) | (d & 7);
        dst[dcol] = f2bf(acc[mb][nd][r] * inv);
      }
    }
}

// ------------------------------------------------------------ out projection
// out[m,n] = sum_k ctx[m,k]*Wo[n,k] + bo[n], fp32 out. 128m x 64n tiles,
// grid (16,32) = 512 blocks; double-buffered gl2lds, one barrier per iter.
__global__ __launch_bounds__(256) void gemm_out(
    const u16* __restrict__ cb, const u16* __restrict__ wob,
    const float* __restrict__ bo, float* __restrict__ out) {
  __shared__ u16 smem[24576];  // As[2][8192] | Bs[2][4096] = 48 KB
  u16* As = smem;
  u16* Bs = smem + 16384;
  const int tid = threadIdx.x, lane = tid & 63;
  const int wid = tid >> 6;
  const int l15 = lane & 15, lg = lane >> 4;
  const int m0 = blockIdx.y * 128, n0 = blockIdx.x * 64;
  const int sw = ((l15 & 7) << 3);

  f32x4 acc[2][4] = {};

#pragma unroll
  for (int i = 0; i < 4; ++i) {
    int c = i * 256 + tid;
    gl2lds16(cb + (m0 + (c >> 3)) * 1024 + (c & 7) * 8, As + c * 8);
  }
#pragma unroll
  for (int i = 0; i < 2; ++i) {
    int c = i * 256 + tid;
    gl2lds16(wob + (n0 + (c >> 3)) * 1024 + (c & 7) * 8, Bs + c * 8);
  }

  for (int k0 = 0; k0 < 1024; k0 += 64) {
    const int p = (k0 >> 6) & 1;
    __syncthreads();
    if (k0 < 960) {
      u16* An = As + (1 - p) * 8192;
      u16* Bn = Bs + (1 - p) * 4096;
#pragma unroll
      for (int i = 0; i < 4; ++i) {
        int c = i * 256 + tid;
        gl2lds16(cb + (m0 + (c >> 3)) * 1024 + k0 + 64 + (c & 7) * 8, An + c * 8);
      }
#pragma unroll
      for (int i = 0; i < 2; ++i) {
        int c = i * 256 + tid;
        gl2lds16(wob + (n0 + (c >> 3)) * 1024 + k0 + 64 + (c & 7) * 8, Bn + c * 8);
      }
    }
    const u16* Ap = As + p * 8192;
    const u16* Bp = Bs + p * 4096;
#pragma unroll
    for (int kk = 0; kk < 2; ++kk) {
      short8 af[2], bf[4];
#pragma unroll
      for (int mb = 0; mb < 2; ++mb)
        af[mb] = *(const short8*)(Ap + (wid * 32 + mb * 16 + l15) * 64 + ((((kk * 4 + lg) << 3)) ^ sw));
#pragma unroll
      for (int nb = 0; nb < 4; ++nb)
        bf[nb] = *(const short8*)(Bp + (nb * 16 + l15) * 64 + ((((kk * 4 + lg) << 3)) ^ sw));
#pragma unroll
      for (int mb = 0; mb < 2; ++mb)
#pragma unroll
        for (int nb = 0; nb < 4; ++nb)
          acc[mb][nb] = __builtin_amdgcn_mfma_f32_16x16x32_bf16(af[mb], bf[nb], acc[mb][nb], 0, 0, 0);
    }
  }

#pragma unroll
  for (int mb = 0; mb < 2; ++mb)
#pragma unroll
    for (int nb = 0; nb < 4; ++nb)
#pragma unroll
      for (int r = 0; r < 4; ++r) {
        int m = m0 + wid * 32 + mb * 16 + lg * 4 + r;
        int n = n0 + nb * 16 + l15;
        out[m * 1024 + n] = acc[mb][nb][r] + bo[n];
      }
}

// --------------------------------------------------------------------- launch
extern "C" void kernel_launch(void* const* d_in, const int* in_sizes, int n_in,
                              void* d_out, int out_size, void* d_ws, size_t ws_size,
                              hipStream_t stream) {
  const float* x  = (const float*)d_in[0];
  const float* wq = (const float*)d_in[1];
  const float* bq = (const float*)d_in[2];
  const float* wk = (const float*)d_in[3];
  const float* bk = (const float*)d_in[4];
  const float* wv = (const float*)d_in[5];
  const float* bv = (const float*)d_in[6];
  const float* wo = (const float*)d_in[7];
  const float* bo = (const float*)d_in[8];

  if (ws_size < (size_t)24 * 1024 * 1024 * 2) return;
  u16* xb   = (u16*)d_ws;              // chunk-swizzled
  u16* wqb  = xb  + (4u << 20);        // chunk-swizzled
  u16* wkb  = wqb + (1u << 20);
  u16* wvb  = wkb + (1u << 20);
  u16* wob  = wvb + (1u << 20);
  u16* qb   = wob + (1u << 20);        // plain [B,NH,S,D]
  u16* kb   = qb  + (4u << 20);        // chunk-swizzled [B,NH,S,D]
  u16* vtb  = kb  + (4u << 20);        // V^T [B,NH,D,Sperm], chunk-swizzled
  u16* ctxb = vtb + (4u << 20);        // chunk-swizzled [B,S,H]

  cvt_kernel<<<dim3(512, 8, 1), 256, 0, stream>>>(x, wq, wk, wv, wo, xb, wqb, wkb, wvb, wob);
  gemm_qkv<<<dim3(8, 32, 3), 256, 0, stream>>>(xb, wqb, wkb, wvb, bq, bk, bv, qb, kb, vtb);
  attn_kernel<<<dim3(16, 16, 2), 256, 0, stream>>>(qb, kb, vtb, ctxb);
  gemm_out<<<dim3(16, 32, 1), 256, 0, stream>>>(ctxb, wob, bo, (float*)d_out);
}